// Round 2
// baseline (498.819 us; speedup 1.0000x reference)
//
#include <hip/hip_runtime.h>
#include <stdint.h>

// Problem constants (fixed by the reference): B=2, S=2048, D=2048, Dh=64, Hq=32, Hkv=8, G=4.
#define S_LEN   2048
#define D_MODEL 2048
#define DKV     512

typedef __attribute__((ext_vector_type(8))) short short8;   // 8 x bf16 (guide §3 typedef)
typedef __attribute__((ext_vector_type(4))) float f32x4;

__device__ static inline unsigned short f2bf(float f) {     // RNE float->bf16 (finite values)
  unsigned u = __builtin_bit_cast(unsigned, f);
  u += 0x7FFFu + ((u >> 16) & 1u);
  return (unsigned short)(u >> 16);
}
__device__ static inline float bf2f(unsigned short h) {
  return __builtin_bit_cast(float, ((unsigned)h) << 16);
}

__device__ static inline void gload_lds16(const void* g, void* lds) {
  // async global->LDS, 16B/lane; LDS dest = wave-uniform base + lane*16 (guide §5)
  __builtin_amdgcn_global_load_lds((const __attribute__((address_space(1))) void*)g,
                                   (__attribute__((address_space(3))) void*)lds,
                                   16, 0, 0);
}

// fp32 -> bf16 bulk conversion: thread i converts 8 consecutive floats -> one 16B bf16 store.
__global__ __launch_bounds__(256) void cvt_kernel(const float* __restrict__ in,
                                                  unsigned short* __restrict__ out, int n8) {
  const int i = blockIdx.x * 256 + threadIdx.x;
  if (i >= n8) return;
  const float4 a = ((const float4*)in)[i * 2];
  const float4 b = ((const float4*)in)[i * 2 + 1];
  unsigned short u[8] = {f2bf(a.x), f2bf(a.y), f2bf(a.z), f2bf(a.w),
                         f2bf(b.x), f2bf(b.y), f2bf(b.z), f2bf(b.w)};
  *(uint4*)(out + (size_t)i * 8) = *(const uint4*)u;
}

__device__ static inline void storeC(unsigned short* C, size_t idx, float v) { C[idx] = f2bf(v); }
__device__ static inline void storeC(float* C, size_t idx, float v) { C[idx] = v; }

// ---------------- 128x128 bf16 GEMM tile body (m97 structure): C = A(M,K) @ B(N,K)^T ------------
template <typename CT>
__device__ __forceinline__ void gemm128_body(const unsigned short* A, int lda,
                                             const unsigned short* B, int ldb,
                                             CT* C, int ldc,
                                             int m0, int n0, int Kdim,
                                             unsigned short* As, unsigned short* Bs) {
  const int tid  = threadIdx.x;
  const int lane = tid & 63;
  const int w    = tid >> 6;        // 4 waves, 2x2 -> each computes 64x64
  const int wm   = w >> 1, wn = w & 1;
  const int lcol = lane & 15;       // fragment row/col index
  const int lq   = lane >> 4;       // quad

  f32x4 acc[4][4] = {};

  for (int k0 = 0; k0 < Kdim; k0 += 32) {
    __syncthreads();                 // previous iter's LDS reads drained
#pragma unroll
    for (int i = 0; i < 2; ++i) {    // 8 chunks x 1KB cover A(8KB); same for B
      const int c  = i * 4 + w;      // wave-uniform chunk id
      const int e  = c * 512 + lane * 8;   // element index in row-major [128][32] tile
      const int rr = e >> 5;
      const int cc = e & 31;
      gload_lds16(A + (size_t)(m0 + rr) * lda + (k0 + cc), As + c * 512);
      gload_lds16(B + (size_t)(n0 + rr) * ldb + (k0 + cc), Bs + c * 512);
    }
    __syncthreads();                 // compiler emits vmcnt(0) drain before s_barrier

    short8 af[4], bfr[4];
#pragma unroll
    for (int mi = 0; mi < 4; ++mi)
      af[mi] = *(const short8*)&As[(wm * 64 + mi * 16 + lcol) * 32 + lq * 8];
#pragma unroll
    for (int ni = 0; ni < 4; ++ni)
      bfr[ni] = *(const short8*)&Bs[(wn * 64 + ni * 16 + lcol) * 32 + lq * 8];
#pragma unroll
    for (int mi = 0; mi < 4; ++mi)
#pragma unroll
      for (int ni = 0; ni < 4; ++ni)
        acc[mi][ni] = __builtin_amdgcn_mfma_f32_16x16x32_bf16(af[mi], bfr[ni], acc[mi][ni], 0, 0, 0);
  }
  // epilogue: C/D layout col=lane&15, row=quad*4+r (m89/m91-verified)
#pragma unroll
  for (int mi = 0; mi < 4; ++mi)
#pragma unroll
    for (int ni = 0; ni < 4; ++ni)
#pragma unroll
      for (int r = 0; r < 4; ++r) {
        const int row = m0 + wm * 64 + mi * 16 + lq * 4 + r;
        const int col = n0 + wn * 64 + ni * 16 + lcol;
        storeC(C, (size_t)row * ldc + col, acc[mi][ni][r]);
      }
}

// Fused QKV projection: grid.x = 16(Q) + 4(K) + 4(V) N-tiles, grid.y = 32 M-tiles.
__global__ __launch_bounds__(256) void qkv_gemm_kernel(
    const unsigned short* __restrict__ x,
    const unsigned short* __restrict__ Wq, const unsigned short* __restrict__ Wk,
    const unsigned short* __restrict__ Wv,
    unsigned short* __restrict__ Qo, unsigned short* __restrict__ Ko, unsigned short* __restrict__ Vo) {
  __shared__ unsigned short As[128 * 32];
  __shared__ unsigned short Bs[128 * 32];
  const int tn = blockIdx.x;
  const int m0 = blockIdx.y * 128;
  const unsigned short* W; unsigned short* C; int n0, ldc;
  if (tn < 16)      { W = Wq; C = Qo; n0 = tn * 128;        ldc = D_MODEL; }
  else if (tn < 20) { W = Wk; C = Ko; n0 = (tn - 16) * 128; ldc = DKV; }
  else              { W = Wv; C = Vo; n0 = (tn - 20) * 128; ldc = DKV; }
  gemm128_body(x, D_MODEL, W, D_MODEL, C, ldc, m0, n0, D_MODEL, As, Bs);
}

// O-projection: bf16 A (attn out) x bf16 Wo -> fp32 d_out.
__global__ __launch_bounds__(256) void oproj_gemm_kernel(
    const unsigned short* __restrict__ A, const unsigned short* __restrict__ Wo,
    float* __restrict__ C) {
  __shared__ unsigned short As[128 * 32];
  __shared__ unsigned short Bs[128 * 32];
  gemm128_body(A, D_MODEL, Wo, D_MODEL, C, D_MODEL, blockIdx.y * 128, blockIdx.x * 128, D_MODEL, As, Bs);
}

// RoPE in-place on ws Q/K (row = b*S+s, col = h*64+d; interleaved pairs (2i,2i+1)).
// scale folds 1/sqrt(Dh)=0.125 into Q (exact pow-2 in bf16).
__global__ __launch_bounds__(256) void rope_kernel(unsigned short* __restrict__ X,
                                                   int totalPairs, int lgHalf, float scale) {
  const int idx = blockIdx.x * 256 + threadIdx.x;
  if (idx >= totalPairs) return;
  const int half = 1 << lgHalf;
  const int r  = idx >> lgHalf;
  const int cp = idx & (half - 1);
  const int i  = cp & 31;                 // pair index within head
  const int s  = r & (S_LEN - 1);         // position
  const float inv = exp2f(-13.287712379549449f * (float)(2 * i) * (1.0f / 64.0f)); // 10000^(-2i/64)
  const float th  = (float)s * inv;
  const float c = cosf(th), sn = sinf(th);
  unsigned short* p = X + ((size_t)r << (lgHalf + 1)) + 2 * cp;
  const float x0 = bf2f(p[0]), x1 = bf2f(p[1]);
  p[0] = f2bf((x0 * c - x1 * sn) * scale);
  p[1] = f2bf((x0 * sn + x1 * c) * scale);
}

// Flash attention: block = (b, hq, 64-row q-tile), 4 waves x 16 rows each.
__global__ __launch_bounds__(256) void attn_kernel(const unsigned short* __restrict__ Q,
                                                   const unsigned short* __restrict__ K,
                                                   const unsigned short* __restrict__ V,
                                                   unsigned short* __restrict__ O) {
  const int q0 = blockIdx.x * 64;
  const int hq = blockIdx.y;
  const int b  = blockIdx.z;
  const int hk = hq >> 2;                 // G=4: q head (kv*G+g) -> kv = hq/4
  const int tid  = threadIdx.x;
  const int lane = tid & 63;
  const int w    = tid >> 6;
  const int lcol = lane & 15;
  const int lq   = lane >> 4;

  // pad 72 (144B rows): keeps 16B alignment for ds_read_b128, breaks pow-2 bank stride
  __shared__ unsigned short Qs[64 * 72];
  __shared__ unsigned short Ks[64 * 72];
  __shared__ unsigned short Vt[64 * 72];  // V transposed: [d][key]
  __shared__ unsigned short Ps[64 * 72];  // P rows, per-wave private 16-row regions

  { // stage Q tile (64 rows x 64 dims)
    const int t  = tid >> 2;
    const int dp = (tid & 3) * 16;
    const unsigned short* g = Q + (size_t)(b * S_LEN + q0 + t) * D_MODEL + hq * 64 + dp;
    *(uint4*)&Qs[t * 72 + dp]     = *(const uint4*)g;
    *(uint4*)&Qs[t * 72 + dp + 8] = *(const uint4*)(g + 8);
  }
  __syncthreads();

  short8 qf[2];                           // A-frags for wave's 16 rows, K=64 -> 2 slabs
#pragma unroll
  for (int ks = 0; ks < 2; ++ks)
    qf[ks] = *(const short8*)&Qs[(w * 16 + lcol) * 72 + ks * 32 + lq * 8];

  f32x4 Oacc[4] = {};
  float m_i[4], l_i[4];
#pragma unroll
  for (int r = 0; r < 4; ++r) { m_i[r] = -3e38f; l_i[r] = 0.f; }

  for (int t0 = 0; t0 <= q0; t0 += 64) {
    __syncthreads();                      // protect K/V LDS reuse
    { // stage K tile [key][d] and V transposed [d][key]
      const int t  = tid >> 2;
      const int dp = (tid & 3) * 16;
      const unsigned short* gk = K + (size_t)(b * S_LEN + t0 + t) * DKV + hk * 64 + dp;
      *(uint4*)&Ks[t * 72 + dp]     = *(const uint4*)gk;
      *(uint4*)&Ks[t * 72 + dp + 8] = *(const uint4*)(gk + 8);
      const unsigned short* gv = V + (size_t)(b * S_LEN + t0 + t) * DKV + hk * 64 + dp;
      unsigned short tmp[16];
      *(uint4*)&tmp[0] = *(const uint4*)gv;
      *(uint4*)&tmp[8] = *(const uint4*)(gv + 8);
#pragma unroll
      for (int j = 0; j < 16; ++j) Vt[(dp + j) * 72 + t] = tmp[j];
    }
    __syncthreads();

    // S = Q @ K^T  (b-frag: n=key=lane&15, k=d contiguous from Ks[key][d])
    f32x4 Sacc[4] = {};
#pragma unroll
    for (int ks = 0; ks < 2; ++ks)
#pragma unroll
      for (int nt = 0; nt < 4; ++nt) {
        const short8 kf = *(const short8*)&Ks[(nt * 16 + lcol) * 72 + ks * 32 + lq * 8];
        Sacc[nt] = __builtin_amdgcn_mfma_f32_16x16x32_bf16(qf[ks], kf, Sacc[nt], 0, 0, 0);
      }

    if (t0 == q0) {                       // only the diagonal tile needs masking
#pragma unroll
      for (int nt = 0; nt < 4; ++nt) {
        const int key = t0 + nt * 16 + lcol;
#pragma unroll
        for (int r = 0; r < 4; ++r) {
          const int rowp = q0 + w * 16 + lq * 4 + r;
          if (key > rowp) Sacc[nt][r] = -1e30f;
        }
      }
    }

    // online softmax per row (row = w*16 + lq*4 + r; 16 lanes share a row-group)
#pragma unroll
    for (int r = 0; r < 4; ++r) {
      float mx = fmaxf(fmaxf(Sacc[0][r], Sacc[1][r]), fmaxf(Sacc[2][r], Sacc[3][r]));
#pragma unroll
      for (int off = 1; off < 16; off <<= 1) mx = fmaxf(mx, __shfl_xor(mx, off));
      const float mnew  = fmaxf(m_i[r], mx);
      const float alpha = __expf(m_i[r] - mnew);
      float rs = 0.f;
#pragma unroll
      for (int nt = 0; nt < 4; ++nt) {
        const float p = __expf(Sacc[nt][r] - mnew);
        Sacc[nt][r] = p;
        rs += p;
      }
#pragma unroll
      for (int off = 1; off < 16; off <<= 1) rs += __shfl_xor(rs, off);
      m_i[r] = mnew;
      l_i[r] = l_i[r] * alpha + rs;
#pragma unroll
      for (int dt = 0; dt < 4; ++dt) Oacc[dt][r] *= alpha;
      const int prow = w * 16 + lq * 4 + r;       // C-layout -> LDS (A-layout re-read below)
#pragma unroll
      for (int nt = 0; nt < 4; ++nt)
        Ps[prow * 72 + nt * 16 + lcol] = f2bf(Sacc[nt][r]);
    }
    asm volatile("s_waitcnt lgkmcnt(0)" ::: "memory");  // per-wave P write->read ordering

    // O += P @ V  (a-frag from Ps rows; b-frag: n=d, k=key contiguous from Vt[d][key])
#pragma unroll
    for (int ks = 0; ks < 2; ++ks) {
      const short8 pf = *(const short8*)&Ps[(w * 16 + lcol) * 72 + ks * 32 + lq * 8];
#pragma unroll
      for (int dt = 0; dt < 4; ++dt) {
        const short8 vf = *(const short8*)&Vt[(dt * 16 + lcol) * 72 + ks * 32 + lq * 8];
        Oacc[dt] = __builtin_amdgcn_mfma_f32_16x16x32_bf16(pf, vf, Oacc[dt], 0, 0, 0);
      }
    }
  }

#pragma unroll
  for (int dt = 0; dt < 4; ++dt)
#pragma unroll
    for (int r = 0; r < 4; ++r) {
      const int row = q0 + w * 16 + lq * 4 + r;
      const int col = hq * 64 + dt * 16 + lcol;
      O[(size_t)(b * S_LEN + row) * D_MODEL + col] = f2bf(Oacc[dt][r] / l_i[r]);
    }
}

extern "C" void kernel_launch(void* const* d_in, const int* in_sizes, int n_in,
                              void* d_out, int out_size, void* d_ws, size_t ws_size,
                              hipStream_t stream) {
  const float* x  = (const float*)d_in[0];   // fp32 inputs per the reference dtypes
  const float* Wq = (const float*)d_in[1];
  const float* Wk = (const float*)d_in[2];
  const float* Wv = (const float*)d_in[3];
  const float* Wo = (const float*)d_in[4];
  float* out = (float*)d_out;                // fp32 output per the reference

  // Workspace (bf16 elements), total ~76 MiB:
  unsigned short* Qb  = (unsigned short*)d_ws;                 // 4096 x 2048
  unsigned short* Kb  = Qb  + (size_t)4096 * 2048;             // 4096 x 512
  unsigned short* Vb  = Kb  + (size_t)4096 * 512;              // 4096 x 512
  unsigned short* Ab  = Vb  + (size_t)4096 * 512;              // 4096 x 2048
  unsigned short* xb  = Ab  + (size_t)4096 * 2048;             // 4096 x 2048
  unsigned short* Wqb = xb  + (size_t)4096 * 2048;             // 2048 x 2048
  unsigned short* Wkb = Wqb + (size_t)2048 * 2048;             // 512 x 2048
  unsigned short* Wvb = Wkb + (size_t)512 * 2048;              // 512 x 2048
  unsigned short* Wob = Wvb + (size_t)512 * 2048;              // 2048 x 2048

  const int n8_x  = (2 * S_LEN * D_MODEL) / 8;
  const int n8_wq = (D_MODEL * D_MODEL) / 8;
  const int n8_wk = (DKV * D_MODEL) / 8;
  cvt_kernel<<<(n8_x + 255) / 256, 256, 0, stream>>>(x, xb, n8_x);
  cvt_kernel<<<(n8_wq + 255) / 256, 256, 0, stream>>>(Wq, Wqb, n8_wq);
  cvt_kernel<<<(n8_wk + 255) / 256, 256, 0, stream>>>(Wk, Wkb, n8_wk);
  cvt_kernel<<<(n8_wk + 255) / 256, 256, 0, stream>>>(Wv, Wvb, n8_wk);
  cvt_kernel<<<(n8_wq + 255) / 256, 256, 0, stream>>>(Wo, Wob, n8_wq);

  qkv_gemm_kernel<<<dim3(24, 32), 256, 0, stream>>>(xb, Wqb, Wkb, Wvb, Qb, Kb, Vb);
  rope_kernel<<<(4096 * 1024) / 256, 256, 0, stream>>>(Qb, 4096 * 1024, 10, 0.125f); // Q: scale folded
  rope_kernel<<<(4096 * 256) / 256, 256, 0, stream>>>(Kb, 4096 * 256, 8, 1.0f);      // K
  attn_kernel<<<dim3(32, 32, 2), 256, 0, stream>>>(Qb, Kb, Vb, Ab);
  oproj_gemm_kernel<<<dim3(16, 32), 256, 0, stream>>>(Ab, Wob, out);
}

// Round 4
// 357.889 us; speedup vs baseline: 1.3938x; 1.3938x over previous
//
#include <hip/hip_runtime.h>
#include <stdint.h>

// Problem constants (fixed by the reference): B=2, S=2048, D=2048, Dh=64, Hq=32, Hkv=8, G=4.
#define S_LEN   2048
#define D_MODEL 2048
#define DKV     512

typedef __attribute__((ext_vector_type(8))) short short8;   // 8 x bf16
typedef __attribute__((ext_vector_type(4))) float f32x4;

__device__ static inline unsigned short f2bf(float f) {     // RNE float->bf16 (finite values)
  unsigned u = __builtin_bit_cast(unsigned, f);
  u += 0x7FFFu + ((u >> 16) & 1u);
  return (unsigned short)(u >> 16);
}
__device__ static inline float bf2f(unsigned short h) {
  return __builtin_bit_cast(float, ((unsigned)h) << 16);
}

__device__ static inline void gload_lds16(const void* g, void* lds) {
  __builtin_amdgcn_global_load_lds((const __attribute__((address_space(1))) void*)g,
                                   (__attribute__((address_space(3))) void*)lds,
                                   16, 0, 0);
}

// fp32 -> bf16 bulk conversion for all 5 inputs in ONE launch (exact region split, units of 8 floats).
__global__ __launch_bounds__(256) void cvt_all_kernel(
    const float* __restrict__ x, const float* __restrict__ wq, const float* __restrict__ wk,
    const float* __restrict__ wv, const float* __restrict__ wo,
    unsigned short* __restrict__ xb, unsigned short* __restrict__ wqb,
    unsigned short* __restrict__ wkb, unsigned short* __restrict__ wvb,
    unsigned short* __restrict__ wob) {
  int i = blockIdx.x * 256 + threadIdx.x;          // 0 .. 2359296-1
  const float* s; unsigned short* d;
  if (i < 1048576)      { s = x;  d = xb;  }
  else if (i < 1572864) { s = wq; d = wqb; i -= 1048576; }
  else if (i < 1703936) { s = wk; d = wkb; i -= 1572864; }
  else if (i < 1835008) { s = wv; d = wvb; i -= 1703936; }
  else                  { s = wo; d = wob; i -= 1835008; }
  const float4 a = ((const float4*)s)[i * 2];
  const float4 b = ((const float4*)s)[i * 2 + 1];
  unsigned short u[8] = {f2bf(a.x), f2bf(a.y), f2bf(a.z), f2bf(a.w),
                         f2bf(b.x), f2bf(b.y), f2bf(b.z), f2bf(b.w)};
  *(uint4*)(d + (size_t)i * 8) = *(const uint4*)u;
}

__device__ static inline void storeC(unsigned short* C, size_t idx, float v) { C[idx] = f2bf(v); }
__device__ static inline void storeC(float* C, size_t idx, float v) { C[idx] = v; }

// ---------------- 128x128 bf16 GEMM tile body (m97 structure): C = A(M,K) @ B(N,K)^T ------------
// CMODE 0: row-major C. CMODE 1: V-transpose epilogue -> C[(b*512+col)*2048 + s] (CT=bf16).
template <int CMODE, typename CT>
__device__ __forceinline__ void gemm128_body(const unsigned short* A, int lda,
                                             const unsigned short* B, int ldb,
                                             CT* C, int ldc,
                                             int m0, int n0, int Kdim,
                                             unsigned short* As, unsigned short* Bs) {
  const int tid  = threadIdx.x;
  const int lane = tid & 63;
  const int w    = tid >> 6;        // 4 waves, 2x2 -> each computes 64x64
  const int wm   = w >> 1, wn = w & 1;
  const int lcol = lane & 15;
  const int lq   = lane >> 4;

  f32x4 acc[4][4] = {};

  for (int k0 = 0; k0 < Kdim; k0 += 32) {
    __syncthreads();
#pragma unroll
    for (int i = 0; i < 2; ++i) {
      const int c  = i * 4 + w;
      const int e  = c * 512 + lane * 8;
      const int rr = e >> 5;
      const int cc = e & 31;
      gload_lds16(A + (size_t)(m0 + rr) * lda + (k0 + cc), As + c * 512);
      gload_lds16(B + (size_t)(n0 + rr) * ldb + (k0 + cc), Bs + c * 512);
    }
    __syncthreads();

    short8 af[4], bfr[4];
#pragma unroll
    for (int mi = 0; mi < 4; ++mi)
      af[mi] = *(const short8*)&As[(wm * 64 + mi * 16 + lcol) * 32 + lq * 8];
#pragma unroll
    for (int ni = 0; ni < 4; ++ni)
      bfr[ni] = *(const short8*)&Bs[(wn * 64 + ni * 16 + lcol) * 32 + lq * 8];
#pragma unroll
    for (int mi = 0; mi < 4; ++mi)
#pragma unroll
      for (int ni = 0; ni < 4; ++ni)
        acc[mi][ni] = __builtin_amdgcn_mfma_f32_16x16x32_bf16(af[mi], bfr[ni], acc[mi][ni], 0, 0, 0);
  }
#pragma unroll
  for (int mi = 0; mi < 4; ++mi)
#pragma unroll
    for (int ni = 0; ni < 4; ++ni)
#pragma unroll
      for (int r = 0; r < 4; ++r) {
        const int row = m0 + wm * 64 + mi * 16 + lq * 4 + r;
        const int col = n0 + wn * 64 + ni * 16 + lcol;
        if constexpr (CMODE == 1) {
          // V pre-transpose: row = b*2048+s, col = d(0..511) -> Vt[(b*512+d)*2048 + s]
          C[((size_t)((row >> 11) * 512 + col)) * 2048 + (row & 2047)] = f2bf(acc[mi][ni][r]);
        } else {
          storeC(C, (size_t)row * ldc + col, acc[mi][ni][r]);
        }
      }
}

// Fused QKV projection: grid.x = 16(Q) + 4(K) + 4(V) N-tiles, grid.y = 32 M-tiles.
__global__ __launch_bounds__(256) void qkv_gemm_kernel(
    const unsigned short* __restrict__ x,
    const unsigned short* __restrict__ Wq, const unsigned short* __restrict__ Wk,
    const unsigned short* __restrict__ Wv,
    unsigned short* __restrict__ Qo, unsigned short* __restrict__ Ko, unsigned short* __restrict__ Vt) {
  __shared__ unsigned short As[128 * 32];
  __shared__ unsigned short Bs[128 * 32];
  const int tn = blockIdx.x;
  const int m0 = blockIdx.y * 128;
  if (tn < 16) {
    gemm128_body<0>(x, D_MODEL, Wq, D_MODEL, Qo, D_MODEL, m0, tn * 128, D_MODEL, As, Bs);
  } else if (tn < 20) {
    gemm128_body<0>(x, D_MODEL, Wk, D_MODEL, Ko, DKV, m0, (tn - 16) * 128, D_MODEL, As, Bs);
  } else {
    gemm128_body<1>(x, D_MODEL, Wv, D_MODEL, Vt, DKV, m0, (tn - 20) * 128, D_MODEL, As, Bs);
  }
}

// O-projection: bf16 A (attn out) x bf16 Wo -> fp32 d_out.
__global__ __launch_bounds__(256) void oproj_gemm_kernel(
    const unsigned short* __restrict__ A, const unsigned short* __restrict__ Wo,
    float* __restrict__ C) {
  __shared__ unsigned short As[128 * 32];
  __shared__ unsigned short Bs[128 * 32];
  gemm128_body<0>(A, D_MODEL, Wo, D_MODEL, C, D_MODEL,
                  blockIdx.y * 128, blockIdx.x * 128, D_MODEL, As, Bs);
}

// RoPE in-place on ws Q/K (row = b*S+s, col = h*64+d; interleaved pairs (2i,2i+1)).
__global__ __launch_bounds__(256) void rope_kernel(unsigned short* __restrict__ X,
                                                   int totalPairs, int lgHalf, float scale) {
  const int idx = blockIdx.x * 256 + threadIdx.x;
  if (idx >= totalPairs) return;
  const int half = 1 << lgHalf;
  const int r  = idx >> lgHalf;
  const int cp = idx & (half - 1);
  const int i  = cp & 31;
  const int s  = r & (S_LEN - 1);
  const float inv = exp2f(-13.287712379549449f * (float)(2 * i) * (1.0f / 64.0f)); // 10000^(-2i/64)
  const float th  = (float)s * inv;
  const float c = cosf(th), sn = sinf(th);
  unsigned short* p = X + ((size_t)r << (lgHalf + 1)) + 2 * cp;
  const float x0 = bf2f(p[0]), x1 = bf2f(p[1]);
  p[0] = f2bf((x0 * c - x1 * sn) * scale);
  p[1] = f2bf((x0 * sn + x1 * c) * scale);
}

// Flash attention with causal pairing: block x handles q-tiles x and 31-x (33 key-tiles total).
// Grid (16, 32, 2). 4 waves; wave w owns q-rows w*16..w*16+15 of the 64-row tile.
// K/V tile t+1 register-prefetched while computing tile t. V comes pre-transposed (Vt global).
__global__ __launch_bounds__(256, 4) void attn_kernel(const unsigned short* __restrict__ Q,
                                                      const unsigned short* __restrict__ K,
                                                      const unsigned short* __restrict__ Vt,
                                                      unsigned short* __restrict__ O) {
  const int hq = blockIdx.y;
  const int bb = blockIdx.z;
  const int hk = hq >> 2;
  const int tid  = threadIdx.x;
  const int lane = tid & 63;
  const int w    = tid >> 6;
  const int lcol = lane & 15;
  const int lq   = lane >> 4;
  const int trow = tid >> 2;            // staging row 0..63
  const int tq   = (tid & 3) * 16;      // staging col quarter (16 elems = 32B)

  // 72-elem rows: 16B-aligned (144B), breaks pow-2 bank stride. QPs doubles as Q then P.
  __shared__ unsigned short QPs[64 * 72];
  __shared__ unsigned short Ks[64 * 72];
  __shared__ unsigned short Vts[64 * 72];

  for (int pass = 0; pass < 2; ++pass) {
    const int qt = pass ? (31 - (int)blockIdx.x) : (int)blockIdx.x;
    const int q0 = qt * 64;
    const int ntiles = qt + 1;

    // prefetch K/V tile 0 into registers (in flight across Q staging)
    uint4 kp0, kp1, vp0, vp1;
    {
      const unsigned short* gk = K + ((size_t)(bb * S_LEN + 0 + trow)) * DKV + hk * 64 + tq;
      kp0 = *(const uint4*)gk; kp1 = *(const uint4*)(gk + 8);
      const unsigned short* gv = Vt + ((size_t)(bb * DKV + hk * 64 + trow)) * S_LEN + 0 + tq;
      vp0 = *(const uint4*)gv; vp1 = *(const uint4*)(gv + 8);
    }

    __syncthreads();                    // prev pass LDS reads drained
    { // stage Q tile
      const unsigned short* g = Q + ((size_t)(bb * S_LEN + q0 + trow)) * D_MODEL + hq * 64 + tq;
      *(uint4*)&QPs[trow * 72 + tq]     = *(const uint4*)g;
      *(uint4*)&QPs[trow * 72 + tq + 8] = *(const uint4*)(g + 8);
    }
    __syncthreads();

    short8 qf[2];
#pragma unroll
    for (int ks = 0; ks < 2; ++ks)
      qf[ks] = *(const short8*)&QPs[(w * 16 + lcol) * 72 + ks * 32 + lq * 8];

    f32x4 Oacc[4] = {};
    float m_i[4], l_i[4];
#pragma unroll
    for (int r = 0; r < 4; ++r) { m_i[r] = -3e38f; l_i[r] = 0.f; }

    for (int it = 0; it < ntiles; ++it) {
      __syncthreads();                  // all waves done reading Ks/Vts of iter it-1
      *(uint4*)&Ks[trow * 72 + tq]      = kp0;
      *(uint4*)&Ks[trow * 72 + tq + 8]  = kp1;
      *(uint4*)&Vts[trow * 72 + tq]     = vp0;
      *(uint4*)&Vts[trow * 72 + tq + 8] = vp1;
      if (it + 1 < ntiles) {            // prefetch next tile
        const int t1 = (it + 1) * 64;
        const unsigned short* gk = K + ((size_t)(bb * S_LEN + t1 + trow)) * DKV + hk * 64 + tq;
        kp0 = *(const uint4*)gk; kp1 = *(const uint4*)(gk + 8);
        const unsigned short* gv = Vt + ((size_t)(bb * DKV + hk * 64 + trow)) * S_LEN + t1 + tq;
        vp0 = *(const uint4*)gv; vp1 = *(const uint4*)(gv + 8);
      }
      __syncthreads();

      // S = Q @ K^T
      f32x4 Sacc[4] = {};
#pragma unroll
      for (int ks = 0; ks < 2; ++ks)
#pragma unroll
        for (int nt = 0; nt < 4; ++nt) {
          const short8 kf = *(const short8*)&Ks[(nt * 16 + lcol) * 72 + ks * 32 + lq * 8];
          Sacc[nt] = __builtin_amdgcn_mfma_f32_16x16x32_bf16(qf[ks], kf, Sacc[nt], 0, 0, 0);
        }

      if (it == ntiles - 1) {           // diagonal tile: t0 == q0
#pragma unroll
        for (int nt = 0; nt < 4; ++nt) {
          const int key = q0 + nt * 16 + lcol;
#pragma unroll
          for (int r = 0; r < 4; ++r) {
            const int rowp = q0 + w * 16 + lq * 4 + r;
            if (key > rowp) Sacc[nt][r] = -1e30f;
          }
        }
      }

      // online softmax per row (16 lanes share a row-group)
#pragma unroll
      for (int r = 0; r < 4; ++r) {
        float mx = fmaxf(fmaxf(Sacc[0][r], Sacc[1][r]), fmaxf(Sacc[2][r], Sacc[3][r]));
#pragma unroll
        for (int off = 1; off < 16; off <<= 1) mx = fmaxf(mx, __shfl_xor(mx, off));
        const float mnew  = fmaxf(m_i[r], mx);
        const float alpha = __expf(m_i[r] - mnew);
        float rs = 0.f;
#pragma unroll
        for (int nt = 0; nt < 4; ++nt) {
          const float p = __expf(Sacc[nt][r] - mnew);
          Sacc[nt][r] = p;
          rs += p;
        }
#pragma unroll
        for (int off = 1; off < 16; off <<= 1) rs += __shfl_xor(rs, off);
        m_i[r] = mnew;
        l_i[r] = l_i[r] * alpha + rs;
#pragma unroll
        for (int dt = 0; dt < 4; ++dt) Oacc[dt][r] *= alpha;
        const int prow = w * 16 + lq * 4 + r;     // C-layout -> LDS (wave-private rows)
#pragma unroll
        for (int nt = 0; nt < 4; ++nt)
          QPs[prow * 72 + nt * 16 + lcol] = f2bf(Sacc[nt][r]);
      }
      asm volatile("s_waitcnt lgkmcnt(0)" ::: "memory");  // per-wave P write->read ordering

      // O += P @ V
#pragma unroll
      for (int ks = 0; ks < 2; ++ks) {
        const short8 pf = *(const short8*)&QPs[(w * 16 + lcol) * 72 + ks * 32 + lq * 8];
#pragma unroll
        for (int dt = 0; dt < 4; ++dt) {
          const short8 vf = *(const short8*)&Vts[(dt * 16 + lcol) * 72 + ks * 32 + lq * 8];
          Oacc[dt] = __builtin_amdgcn_mfma_f32_16x16x32_bf16(pf, vf, Oacc[dt], 0, 0, 0);
        }
      }
    }

#pragma unroll
    for (int dt = 0; dt < 4; ++dt)
#pragma unroll
      for (int r = 0; r < 4; ++r) {
        const int row = q0 + w * 16 + lq * 4 + r;
        const int col = hq * 64 + dt * 16 + lcol;
        O[(size_t)(bb * S_LEN + row) * D_MODEL + col] = f2bf(Oacc[dt][r] / l_i[r]);
      }
  }
}

extern "C" void kernel_launch(void* const* d_in, const int* in_sizes, int n_in,
                              void* d_out, int out_size, void* d_ws, size_t ws_size,
                              hipStream_t stream) {
  const float* x  = (const float*)d_in[0];   // fp32 inputs per the reference dtypes
  const float* Wq = (const float*)d_in[1];
  const float* Wk = (const float*)d_in[2];
  const float* Wv = (const float*)d_in[3];
  const float* Wo = (const float*)d_in[4];
  float* out = (float*)d_out;                // fp32 output per the reference

  // Workspace (bf16 elements), total ~70 MiB:
  unsigned short* Qb  = (unsigned short*)d_ws;                 // 4096 x 2048
  unsigned short* Kb  = Qb  + (size_t)4096 * 2048;             // 4096 x 512
  unsigned short* Vtg = Kb  + (size_t)4096 * 512;              // 1024 x 2048 (V pre-transposed)
  unsigned short* Ab  = Vtg + (size_t)1024 * 2048;             // 4096 x 2048
  unsigned short* xb  = Ab  + (size_t)4096 * 2048;             // 4096 x 2048
  unsigned short* Wqb = xb  + (size_t)4096 * 2048;             // 2048 x 2048
  unsigned short* Wkb = Wqb + (size_t)2048 * 2048;             // 512 x 2048
  unsigned short* Wvb = Wkb + (size_t)512 * 2048;              // 512 x 2048
  unsigned short* Wob = Wvb + (size_t)512 * 2048;              // 2048 x 2048

  cvt_all_kernel<<<9216, 256, 0, stream>>>(x, Wq, Wk, Wv, Wo, xb, Wqb, Wkb, Wvb, Wob);

  qkv_gemm_kernel<<<dim3(24, 32), 256, 0, stream>>>(xb, Wqb, Wkb, Wvb, Qb, Kb, Vtg);
  rope_kernel<<<(4096 * 1024) / 256, 256, 0, stream>>>(Qb, 4096 * 1024, 10, 0.125f); // Q: scale folded
  rope_kernel<<<(4096 * 256) / 256, 256, 0, stream>>>(Kb, 4096 * 256, 8, 1.0f);      // K
  attn_kernel<<<dim3(16, 32, 2), 256, 0, stream>>>(Qb, Kb, Vtg, Ab);
  oproj_gemm_kernel<<<dim3(16, 32), 256, 0, stream>>>(Ab, Wob, out);
}

// Round 5
// 323.917 us; speedup vs baseline: 1.5400x; 1.1049x over previous
//
#include <hip/hip_runtime.h>
#include <stdint.h>

// Problem constants (fixed by the reference): B=2, S=2048, D=2048, Dh=64, Hq=32, Hkv=8, G=4.
#define S_LEN   2048
#define D_MODEL 2048
#define DKV     512

typedef __attribute__((ext_vector_type(8))) short short8;   // 8 x bf16
typedef __attribute__((ext_vector_type(4))) float f32x4;

__device__ static inline unsigned short f2bf(float f) {     // RNE float->bf16 (finite values)
  unsigned u = __builtin_bit_cast(unsigned, f);
  u += 0x7FFFu + ((u >> 16) & 1u);
  return (unsigned short)(u >> 16);
}
__device__ static inline float bf2f(unsigned short h) {
  return __builtin_bit_cast(float, ((unsigned)h) << 16);
}

__device__ static inline void gload_lds16(const void* g, void* lds) {
  __builtin_amdgcn_global_load_lds((const __attribute__((address_space(1))) void*)g,
                                   (__attribute__((address_space(3))) void*)lds,
                                   16, 0, 0);
}

// fp32 -> bf16 bulk conversion for all 5 inputs in ONE launch (exact region split, units of 8 floats).
__global__ __launch_bounds__(256) void cvt_all_kernel(
    const float* __restrict__ x, const float* __restrict__ wq, const float* __restrict__ wk,
    const float* __restrict__ wv, const float* __restrict__ wo,
    unsigned short* __restrict__ xb, unsigned short* __restrict__ wqb,
    unsigned short* __restrict__ wkb, unsigned short* __restrict__ wvb,
    unsigned short* __restrict__ wob) {
  int i = blockIdx.x * 256 + threadIdx.x;          // 0 .. 2359296-1
  const float* s; unsigned short* d;
  if (i < 1048576)      { s = x;  d = xb;  }
  else if (i < 1572864) { s = wq; d = wqb; i -= 1048576; }
  else if (i < 1703936) { s = wk; d = wkb; i -= 1572864; }
  else if (i < 1835008) { s = wv; d = wvb; i -= 1703936; }
  else                  { s = wo; d = wob; i -= 1835008; }
  const float4 a = ((const float4*)s)[i * 2];
  const float4 b = ((const float4*)s)[i * 2 + 1];
  unsigned short u[8] = {f2bf(a.x), f2bf(a.y), f2bf(a.z), f2bf(a.w),
                         f2bf(b.x), f2bf(b.y), f2bf(b.z), f2bf(b.w)};
  *(uint4*)(d + (size_t)i * 8) = *(const uint4*)u;
}

__device__ static inline void storeC(unsigned short* C, size_t idx, float v) { C[idx] = f2bf(v); }
__device__ static inline void storeC(float* C, size_t idx, float v) { C[idx] = v; }

// ---------------- 128x128 bf16 GEMM tile body (m97 structure): C = A(M,K) @ B(N,K)^T ------------
// CMODE 0: row-major C. CMODE 1: V-transpose epilogue -> C[(b*512+col)*2048 + s] (CT=bf16).
template <int CMODE, typename CT>
__device__ __forceinline__ void gemm128_body(const unsigned short* A, int lda,
                                             const unsigned short* B, int ldb,
                                             CT* C, int ldc,
                                             int m0, int n0, int Kdim,
                                             unsigned short* As, unsigned short* Bs) {
  const int tid  = threadIdx.x;
  const int lane = tid & 63;
  const int w    = tid >> 6;        // 4 waves, 2x2 -> each computes 64x64
  const int wm   = w >> 1, wn = w & 1;
  const int lcol = lane & 15;
  const int lq   = lane >> 4;

  f32x4 acc[4][4] = {};

  for (int k0 = 0; k0 < Kdim; k0 += 32) {
    __syncthreads();
#pragma unroll
    for (int i = 0; i < 2; ++i) {
      const int c  = i * 4 + w;
      const int e  = c * 512 + lane * 8;
      const int rr = e >> 5;
      const int cc = e & 31;
      gload_lds16(A + (size_t)(m0 + rr) * lda + (k0 + cc), As + c * 512);
      gload_lds16(B + (size_t)(n0 + rr) * ldb + (k0 + cc), Bs + c * 512);
    }
    __syncthreads();

    short8 af[4], bfr[4];
#pragma unroll
    for (int mi = 0; mi < 4; ++mi)
      af[mi] = *(const short8*)&As[(wm * 64 + mi * 16 + lcol) * 32 + lq * 8];
#pragma unroll
    for (int ni = 0; ni < 4; ++ni)
      bfr[ni] = *(const short8*)&Bs[(wn * 64 + ni * 16 + lcol) * 32 + lq * 8];
#pragma unroll
    for (int mi = 0; mi < 4; ++mi)
#pragma unroll
      for (int ni = 0; ni < 4; ++ni)
        acc[mi][ni] = __builtin_amdgcn_mfma_f32_16x16x32_bf16(af[mi], bfr[ni], acc[mi][ni], 0, 0, 0);
  }
#pragma unroll
  for (int mi = 0; mi < 4; ++mi)
#pragma unroll
    for (int ni = 0; ni < 4; ++ni)
#pragma unroll
      for (int r = 0; r < 4; ++r) {
        const int row = m0 + wm * 64 + mi * 16 + lq * 4 + r;
        const int col = n0 + wn * 64 + ni * 16 + lcol;
        if constexpr (CMODE == 1) {
          // V pre-transpose: row = b*2048+s, col = d(0..511) -> Vt[(b*512+d)*2048 + s]
          C[((size_t)((row >> 11) * 512 + col)) * 2048 + (row & 2047)] = f2bf(acc[mi][ni][r]);
        } else {
          storeC(C, (size_t)row * ldc + col, acc[mi][ni][r]);
        }
      }
}

// Fused QKV projection: grid.x = 16(Q) + 4(K) + 4(V) N-tiles, grid.y = 32 M-tiles.
__global__ __launch_bounds__(256) void qkv_gemm_kernel(
    const unsigned short* __restrict__ x,
    const unsigned short* __restrict__ Wq, const unsigned short* __restrict__ Wk,
    const unsigned short* __restrict__ Wv,
    unsigned short* __restrict__ Qo, unsigned short* __restrict__ Ko, unsigned short* __restrict__ Vt) {
  __shared__ unsigned short As[128 * 32];
  __shared__ unsigned short Bs[128 * 32];
  const int tn = blockIdx.x;
  const int m0 = blockIdx.y * 128;
  if (tn < 16) {
    gemm128_body<0>(x, D_MODEL, Wq, D_MODEL, Qo, D_MODEL, m0, tn * 128, D_MODEL, As, Bs);
  } else if (tn < 20) {
    gemm128_body<0>(x, D_MODEL, Wk, D_MODEL, Ko, DKV, m0, (tn - 16) * 128, D_MODEL, As, Bs);
  } else {
    gemm128_body<1>(x, D_MODEL, Wv, D_MODEL, Vt, DKV, m0, (tn - 20) * 128, D_MODEL, As, Bs);
  }
}

// O-projection: bf16 A (attn out) x bf16 Wo -> fp32 d_out.
__global__ __launch_bounds__(256) void oproj_gemm_kernel(
    const unsigned short* __restrict__ A, const unsigned short* __restrict__ Wo,
    float* __restrict__ C) {
  __shared__ unsigned short As[128 * 32];
  __shared__ unsigned short Bs[128 * 32];
  gemm128_body<0>(A, D_MODEL, Wo, D_MODEL, C, D_MODEL,
                  blockIdx.y * 128, blockIdx.x * 128, D_MODEL, As, Bs);
}

// RoPE in-place on ws Q and K in ONE launch (row = b*S+s, col = h*64+d; interleaved pairs).
// Q: 4096 rows x 1024 pairs (scale=0.125 folds 1/sqrt(Dh)); K: 4096 rows x 256 pairs.
__global__ __launch_bounds__(256) void rope_both_kernel(unsigned short* __restrict__ Qb,
                                                        unsigned short* __restrict__ Kb) {
  int idx = blockIdx.x * 256 + threadIdx.x;       // 0 .. 5242879
  unsigned short* X; int lgHalf; float scale;
  if (idx < 4194304) { X = Qb; lgHalf = 10; scale = 0.125f; }
  else               { X = Kb; lgHalf = 8;  scale = 1.0f; idx -= 4194304; }
  const int half = 1 << lgHalf;
  const int r  = idx >> lgHalf;
  const int cp = idx & (half - 1);
  const int i  = cp & 31;
  const int s  = r & (S_LEN - 1);
  const float inv = exp2f(-13.287712379549449f * (float)(2 * i) * (1.0f / 64.0f)); // 10000^(-2i/64)
  const float th  = (float)s * inv;
  const float c = cosf(th), sn = sinf(th);
  unsigned short* p = X + ((size_t)r << (lgHalf + 1)) + 2 * cp;
  const float x0 = bf2f(p[0]), x1 = bf2f(p[1]);
  p[0] = f2bf((x0 * c - x1 * sn) * scale);
  p[1] = f2bf((x0 * sn + x1 * c) * scale);
}

// Flash attention, TRANSPOSED score form: S^T = K@Q^T so each lane owns ONE q-row
// (col=lane&15 of the MFMA C layout). Softmax = in-register tree + 2 shuffles (xor16,32).
// O accumulated as O^T = V^T @ P^T with the same LDS fragment reads.
// Causal pairing: block x handles q-tiles x and 31-x (33 key-tile iters total). Grid (16,32,2).
__global__ __launch_bounds__(256, 4) void attn_kernel(const unsigned short* __restrict__ Q,
                                                      const unsigned short* __restrict__ K,
                                                      const unsigned short* __restrict__ Vt,
                                                      unsigned short* __restrict__ O) {
  const int hq = blockIdx.y;
  const int bb = blockIdx.z;
  const int hk = hq >> 2;
  const int tid  = threadIdx.x;
  const int lane = tid & 63;
  const int w    = tid >> 6;
  const int lcol = lane & 15;
  const int lq   = lane >> 4;
  const int trow = tid >> 2;            // staging row 0..63
  const int tq   = (tid & 3) * 16;      // staging col quarter (16 elems = 32B)

  // 72-elem rows (144B): 16B-aligned, breaks pow-2 bank stride. QPs = Q tile, then P^T rows.
  __shared__ unsigned short QPs[64 * 72];
  __shared__ unsigned short Ks[64 * 72];
  __shared__ unsigned short Vts[64 * 72];

  for (int pass = 0; pass < 2; ++pass) {
    const int qt = pass ? (31 - (int)blockIdx.x) : (int)blockIdx.x;
    const int q0 = qt * 64;
    const int ntiles = qt + 1;
    const int qrow = q0 + w * 16 + lcol;            // this lane's q-row (global)

    // prefetch K/V tile 0 into registers
    uint4 kp0, kp1, vp0, vp1;
    {
      const unsigned short* gk = K + ((size_t)(bb * S_LEN + 0 + trow)) * DKV + hk * 64 + tq;
      kp0 = *(const uint4*)gk; kp1 = *(const uint4*)(gk + 8);
      const unsigned short* gv = Vt + ((size_t)(bb * DKV + hk * 64 + trow)) * S_LEN + 0 + tq;
      vp0 = *(const uint4*)gv; vp1 = *(const uint4*)(gv + 8);
    }

    __syncthreads();                    // prev pass LDS reads drained
    { // stage Q tile (each wave stages exactly its own 16 rows: trow = w*16..w*16+15)
      const unsigned short* g = Q + ((size_t)(bb * S_LEN + q0 + trow)) * D_MODEL + hq * 64 + tq;
      *(uint4*)&QPs[trow * 72 + tq]     = *(const uint4*)g;
      *(uint4*)&QPs[trow * 72 + tq + 8] = *(const uint4*)(g + 8);
    }
    __syncthreads();

    short8 qf[2];                       // B-frag: n = q-row (w*16+lcol), k = d
#pragma unroll
    for (int ks = 0; ks < 2; ++ks)
      qf[ks] = *(const short8*)&QPs[(w * 16 + lcol) * 72 + ks * 32 + lq * 8];

    f32x4 Oacc[4] = {};                 // O^T: col = q-row (lcol), row = d = dt*16+lq*4+r
    float m_i = -3e38f, l_i = 0.f;      // per-lane scalars: one q-row per lane

    for (int it = 0; it < ntiles; ++it) {
      __syncthreads();                  // all waves done reading Ks/Vts of iter it-1
      *(uint4*)&Ks[trow * 72 + tq]      = kp0;
      *(uint4*)&Ks[trow * 72 + tq + 8]  = kp1;
      *(uint4*)&Vts[trow * 72 + tq]     = vp0;
      *(uint4*)&Vts[trow * 72 + tq + 8] = vp1;
      if (it + 1 < ntiles) {            // prefetch next tile
        const int t1 = (it + 1) * 64;
        const unsigned short* gk = K + ((size_t)(bb * S_LEN + t1 + trow)) * DKV + hk * 64 + tq;
        kp0 = *(const uint4*)gk; kp1 = *(const uint4*)(gk + 8);
        const unsigned short* gv = Vt + ((size_t)(bb * DKV + hk * 64 + trow)) * S_LEN + t1 + tq;
        vp0 = *(const uint4*)gv; vp1 = *(const uint4*)(gv + 8);
      }
      __syncthreads();

      // S^T = K @ Q^T : Sacc[nt] holds keys nt*16+lq*4+r for q-row lcol
      f32x4 Sacc[4] = {};
#pragma unroll
      for (int ks = 0; ks < 2; ++ks)
#pragma unroll
        for (int nt = 0; nt < 4; ++nt) {
          const short8 kf = *(const short8*)&Ks[(nt * 16 + lcol) * 72 + ks * 32 + lq * 8];
          Sacc[nt] = __builtin_amdgcn_mfma_f32_16x16x32_bf16(kf, qf[ks], Sacc[nt], 0, 0, 0);
        }

      if (it == ntiles - 1) {           // diagonal tile (t0 == q0): mask key > qrow
#pragma unroll
        for (int nt = 0; nt < 4; ++nt)
#pragma unroll
          for (int r = 0; r < 4; ++r) {
            const int key = q0 + nt * 16 + lq * 4 + r;
            if (key > qrow) Sacc[nt][r] = -1e30f;
          }
      }

      // online softmax: all 16 lane-values belong to q-row lcol; reduce in-register,
      // then across the 4 lq lanes (xor 16, 32).
      float mx = fmaxf(fmaxf(Sacc[0][0], Sacc[0][1]), fmaxf(Sacc[0][2], Sacc[0][3]));
#pragma unroll
      for (int nt = 1; nt < 4; ++nt)
        mx = fmaxf(mx, fmaxf(fmaxf(Sacc[nt][0], Sacc[nt][1]), fmaxf(Sacc[nt][2], Sacc[nt][3])));
      mx = fmaxf(mx, __shfl_xor(mx, 16));
      mx = fmaxf(mx, __shfl_xor(mx, 32));
      const float mnew  = fmaxf(m_i, mx);
      const float alpha = __expf(m_i - mnew);
      float rs = 0.f;
#pragma unroll
      for (int nt = 0; nt < 4; ++nt)
#pragma unroll
        for (int r = 0; r < 4; ++r) {
          const float p = __expf(Sacc[nt][r] - mnew);
          Sacc[nt][r] = p;
          rs += p;
        }
      rs += __shfl_xor(rs, 16);
      rs += __shfl_xor(rs, 32);
      m_i = mnew;
      l_i = l_i * alpha + rs;
#pragma unroll
      for (int dt = 0; dt < 4; ++dt) Oacc[dt] *= alpha;

      // P^T -> LDS as [q-row][key] (B-frag layout for the O^T MFMA): one b64 store per nt
      const int prow = w * 16 + lcol;
#pragma unroll
      for (int nt = 0; nt < 4; ++nt) {
        unsigned short u[4] = {f2bf(Sacc[nt][0]), f2bf(Sacc[nt][1]),
                               f2bf(Sacc[nt][2]), f2bf(Sacc[nt][3])};
        *(uint2*)&QPs[prow * 72 + nt * 16 + lq * 4] = *(const uint2*)u;
      }
      asm volatile("s_waitcnt lgkmcnt(0)" ::: "memory");  // per-wave P write->read ordering

      // O^T += V^T @ P^T  (A-frag: m=d from Vts; B-frag: n=q-row from QPs)
#pragma unroll
      for (int ks = 0; ks < 2; ++ks) {
        const short8 pf = *(const short8*)&QPs[(w * 16 + lcol) * 72 + ks * 32 + lq * 8];
#pragma unroll
        for (int dt = 0; dt < 4; ++dt) {
          const short8 vf = *(const short8*)&Vts[(dt * 16 + lcol) * 72 + ks * 32 + lq * 8];
          Oacc[dt] = __builtin_amdgcn_mfma_f32_16x16x32_bf16(vf, pf, Oacc[dt], 0, 0, 0);
        }
      }
    }

    // epilogue: lane owns q-row `qrow`, d = dt*16 + lq*4 + r (r contiguous -> b64 stores)
    const float inv = 1.0f / l_i;
#pragma unroll
    for (int dt = 0; dt < 4; ++dt) {
      unsigned short u[4] = {f2bf(Oacc[dt][0] * inv), f2bf(Oacc[dt][1] * inv),
                             f2bf(Oacc[dt][2] * inv), f2bf(Oacc[dt][3] * inv)};
      *(uint2*)&O[(size_t)(bb * S_LEN + qrow) * D_MODEL + hq * 64 + dt * 16 + lq * 4] =
          *(const uint2*)u;
    }
  }
}

extern "C" void kernel_launch(void* const* d_in, const int* in_sizes, int n_in,
                              void* d_out, int out_size, void* d_ws, size_t ws_size,
                              hipStream_t stream) {
  const float* x  = (const float*)d_in[0];   // fp32 inputs per the reference dtypes
  const float* Wq = (const float*)d_in[1];
  const float* Wk = (const float*)d_in[2];
  const float* Wv = (const float*)d_in[3];
  const float* Wo = (const float*)d_in[4];
  float* out = (float*)d_out;                // fp32 output per the reference

  // Workspace (bf16 elements), total ~70 MiB:
  unsigned short* Qb  = (unsigned short*)d_ws;                 // 4096 x 2048
  unsigned short* Kb  = Qb  + (size_t)4096 * 2048;             // 4096 x 512
  unsigned short* Vtg = Kb  + (size_t)4096 * 512;              // 1024 x 2048 (V pre-transposed)
  unsigned short* Ab  = Vtg + (size_t)1024 * 2048;             // 4096 x 2048
  unsigned short* xb  = Ab  + (size_t)4096 * 2048;             // 4096 x 2048
  unsigned short* Wqb = xb  + (size_t)4096 * 2048;             // 2048 x 2048
  unsigned short* Wkb = Wqb + (size_t)2048 * 2048;             // 512 x 2048
  unsigned short* Wvb = Wkb + (size_t)512 * 2048;              // 512 x 2048
  unsigned short* Wob = Wvb + (size_t)512 * 2048;              // 2048 x 2048

  cvt_all_kernel<<<9216, 256, 0, stream>>>(x, Wq, Wk, Wv, Wo, xb, Wqb, Wkb, Wvb, Wob);

  qkv_gemm_kernel<<<dim3(24, 32), 256, 0, stream>>>(xb, Wqb, Wkb, Wvb, Qb, Kb, Vtg);
  rope_both_kernel<<<20480, 256, 0, stream>>>(Qb, Kb);
  attn_kernel<<<dim3(16, 32, 2), 256, 0, stream>>>(Qb, Kb, Vtg, Ab);
  oproj_gemm_kernel<<<dim3(16, 32), 256, 0, stream>>>(Ab, Wob, out);
}

// Round 6
// 322.957 us; speedup vs baseline: 1.5445x; 1.0030x over previous
//
#include <hip/hip_runtime.h>
#include <stdint.h>

// Problem constants (fixed by the reference): B=2, S=2048, D=2048, Dh=64, Hq=32, Hkv=8, G=4.
#define S_LEN   2048
#define D_MODEL 2048
#define DKV     512

typedef __attribute__((ext_vector_type(8))) short short8;   // 8 x bf16
typedef __attribute__((ext_vector_type(4))) float f32x4;

__device__ static inline unsigned short f2bf(float f) {     // RNE float->bf16 (finite values)
  unsigned u = __builtin_bit_cast(unsigned, f);
  u += 0x7FFFu + ((u >> 16) & 1u);
  return (unsigned short)(u >> 16);
}
__device__ static inline float bf2f(unsigned short h) {
  return __builtin_bit_cast(float, ((unsigned)h) << 16);
}
// pack hi16(f0), hi16(f1) -> one dword (bf16 truncation; 1 v_perm_b32)
__device__ static inline unsigned packtrunc2(float f0, float f1) {
  return __builtin_amdgcn_perm(__builtin_bit_cast(unsigned, f1),
                               __builtin_bit_cast(unsigned, f0), 0x07060302u);
}

__device__ static inline void gload_lds16(const void* g, void* lds) {
  __builtin_amdgcn_global_load_lds((const __attribute__((address_space(1))) void*)g,
                                   (__attribute__((address_space(3))) void*)lds,
                                   16, 0, 0);
}

// fp32 -> bf16 bulk conversion for all 5 inputs in ONE launch (exact region split, units of 8 floats).
__global__ __launch_bounds__(256) void cvt_all_kernel(
    const float* __restrict__ x, const float* __restrict__ wq, const float* __restrict__ wk,
    const float* __restrict__ wv, const float* __restrict__ wo,
    unsigned short* __restrict__ xb, unsigned short* __restrict__ wqb,
    unsigned short* __restrict__ wkb, unsigned short* __restrict__ wvb,
    unsigned short* __restrict__ wob) {
  int i = blockIdx.x * 256 + threadIdx.x;          // 0 .. 2359296-1
  const float* s; unsigned short* d;
  if (i < 1048576)      { s = x;  d = xb;  }
  else if (i < 1572864) { s = wq; d = wqb; i -= 1048576; }
  else if (i < 1703936) { s = wk; d = wkb; i -= 1572864; }
  else if (i < 1835008) { s = wv; d = wvb; i -= 1703936; }
  else                  { s = wo; d = wob; i -= 1835008; }
  const float4 a = ((const float4*)s)[i * 2];
  const float4 b = ((const float4*)s)[i * 2 + 1];
  unsigned short u[8] = {f2bf(a.x), f2bf(a.y), f2bf(a.z), f2bf(a.w),
                         f2bf(b.x), f2bf(b.y), f2bf(b.z), f2bf(b.w)};
  *(uint4*)(d + (size_t)i * 8) = *(const uint4*)u;
}

__device__ static inline void storeC(unsigned short* C, size_t idx, float v) { C[idx] = f2bf(v); }
__device__ static inline void storeC(float* C, size_t idx, float v) { C[idx] = v; }

// ---------------- 128x128 bf16 GEMM tile body (m97 structure): C = A(M,K) @ B(N,K)^T ------------
// CMODE 0: row-major C. CMODE 1: V-transpose epilogue -> C[(b*512+col)*2048 + s] (CT=bf16).
template <int CMODE, typename CT>
__device__ __forceinline__ void gemm128_body(const unsigned short* A, int lda,
                                             const unsigned short* B, int ldb,
                                             CT* C, int ldc,
                                             int m0, int n0, int Kdim,
                                             unsigned short* As, unsigned short* Bs) {
  const int tid  = threadIdx.x;
  const int lane = tid & 63;
  const int w    = tid >> 6;        // 4 waves, 2x2 -> each computes 64x64
  const int wm   = w >> 1, wn = w & 1;
  const int lcol = lane & 15;
  const int lq   = lane >> 4;

  f32x4 acc[4][4] = {};

  for (int k0 = 0; k0 < Kdim; k0 += 32) {
    __syncthreads();
#pragma unroll
    for (int i = 0; i < 2; ++i) {
      const int c  = i * 4 + w;
      const int e  = c * 512 + lane * 8;
      const int rr = e >> 5;
      const int cc = e & 31;
      gload_lds16(A + (size_t)(m0 + rr) * lda + (k0 + cc), As + c * 512);
      gload_lds16(B + (size_t)(n0 + rr) * ldb + (k0 + cc), Bs + c * 512);
    }
    __syncthreads();

    short8 af[4], bfr[4];
#pragma unroll
    for (int mi = 0; mi < 4; ++mi)
      af[mi] = *(const short8*)&As[(wm * 64 + mi * 16 + lcol) * 32 + lq * 8];
#pragma unroll
    for (int ni = 0; ni < 4; ++ni)
      bfr[ni] = *(const short8*)&Bs[(wn * 64 + ni * 16 + lcol) * 32 + lq * 8];
#pragma unroll
    for (int mi = 0; mi < 4; ++mi)
#pragma unroll
      for (int ni = 0; ni < 4; ++ni)
        acc[mi][ni] = __builtin_amdgcn_mfma_f32_16x16x32_bf16(af[mi], bfr[ni], acc[mi][ni], 0, 0, 0);
  }
#pragma unroll
  for (int mi = 0; mi < 4; ++mi)
#pragma unroll
    for (int ni = 0; ni < 4; ++ni)
#pragma unroll
      for (int r = 0; r < 4; ++r) {
        const int row = m0 + wm * 64 + mi * 16 + lq * 4 + r;
        const int col = n0 + wn * 64 + ni * 16 + lcol;
        if constexpr (CMODE == 1) {
          // V pre-transpose: row = b*2048+s, col = d(0..511) -> Vt[(b*512+d)*2048 + s]
          C[((size_t)((row >> 11) * 512 + col)) * 2048 + (row & 2047)] = f2bf(acc[mi][ni][r]);
        } else {
          storeC(C, (size_t)row * ldc + col, acc[mi][ni][r]);
        }
      }
}

// Fused QKV projection: grid.x = 16(Q) + 4(K) + 4(V) N-tiles, grid.y = 32 M-tiles.
__global__ __launch_bounds__(256) void qkv_gemm_kernel(
    const unsigned short* __restrict__ x,
    const unsigned short* __restrict__ Wq, const unsigned short* __restrict__ Wk,
    const unsigned short* __restrict__ Wv,
    unsigned short* __restrict__ Qo, unsigned short* __restrict__ Ko, unsigned short* __restrict__ Vt) {
  __shared__ unsigned short As[128 * 32];
  __shared__ unsigned short Bs[128 * 32];
  const int tn = blockIdx.x;
  const int m0 = blockIdx.y * 128;
  if (tn < 16) {
    gemm128_body<0>(x, D_MODEL, Wq, D_MODEL, Qo, D_MODEL, m0, tn * 128, D_MODEL, As, Bs);
  } else if (tn < 20) {
    gemm128_body<0>(x, D_MODEL, Wk, D_MODEL, Ko, DKV, m0, (tn - 16) * 128, D_MODEL, As, Bs);
  } else {
    gemm128_body<1>(x, D_MODEL, Wv, D_MODEL, Vt, DKV, m0, (tn - 20) * 128, D_MODEL, As, Bs);
  }
}

// O-projection: bf16 A (attn out) x bf16 Wo -> fp32 d_out.
__global__ __launch_bounds__(256) void oproj_gemm_kernel(
    const unsigned short* __restrict__ A, const unsigned short* __restrict__ Wo,
    float* __restrict__ C) {
  __shared__ unsigned short As[128 * 32];
  __shared__ unsigned short Bs[128 * 32];
  gemm128_body<0>(A, D_MODEL, Wo, D_MODEL, C, D_MODEL,
                  blockIdx.y * 128, blockIdx.x * 128, D_MODEL, As, Bs);
}

// RoPE in-place on ws Q and K in ONE launch (row = b*S+s, col = h*64+d; interleaved pairs).
// Q scale folds 1/sqrt(Dh)*log2(e) = 0.125*1.442695 (log2-domain softmax downstream).
__global__ __launch_bounds__(256) void rope_both_kernel(unsigned short* __restrict__ Qb,
                                                        unsigned short* __restrict__ Kb) {
  int idx = blockIdx.x * 256 + threadIdx.x;       // 0 .. 5242879
  unsigned short* X; int lgHalf; float scale;
  if (idx < 4194304) { X = Qb; lgHalf = 10; scale = 0.1803368801111244f; }
  else               { X = Kb; lgHalf = 8;  scale = 1.0f; idx -= 4194304; }
  const int half = 1 << lgHalf;
  const int r  = idx >> lgHalf;
  const int cp = idx & (half - 1);
  const int i  = cp & 31;
  const int s  = r & (S_LEN - 1);
  const float inv = exp2f(-13.287712379549449f * (float)(2 * i) * (1.0f / 64.0f)); // 10000^(-2i/64)
  const float th  = (float)s * inv;
  const float c = cosf(th), sn = sinf(th);
  unsigned short* p = X + ((size_t)r << (lgHalf + 1)) + 2 * cp;
  const float x0 = bf2f(p[0]), x1 = bf2f(p[1]);
  p[0] = f2bf((x0 * c - x1 * sn) * scale);
  p[1] = f2bf((x0 * sn + x1 * c) * scale);
}

// Flash attention, transposed scores (S^T = K@Q^T, lane owns ONE q-row), MERGED causal pair:
// block x keeps q-tiles A=x and B=31-x live through ONE K/V sweep t=0..31-x (shared staging).
// Scores arrive in log2 domain (Q pre-scaled); softmax uses exp2f. Grid (16,32,2).
__global__ __launch_bounds__(256, 4) void attn_kernel(const unsigned short* __restrict__ Q,
                                                      const unsigned short* __restrict__ K,
                                                      const unsigned short* __restrict__ Vt,
                                                      unsigned short* __restrict__ O) {
  const int hq = blockIdx.y;
  const int bb = blockIdx.z;
  const int hk = hq >> 2;
  const int tid  = threadIdx.x;
  const int lane = tid & 63;
  const int w    = tid >> 6;
  const int lcol = lane & 15;
  const int lq   = lane >> 4;
  const int trow = tid >> 2;            // staging row 0..63 (wave-private: w*16..w*16+15)
  const int tq   = (tid & 3) * 16;      // staging col quarter (16 elems = 32B)

  // 72-elem rows (144B): 16B-aligned, non-pow2 bank stride. Pa/Pb double as Q staging then P^T.
  __shared__ unsigned short Ks[64 * 72];
  __shared__ unsigned short Vts[64 * 72];
  __shared__ unsigned short Pa[64 * 72];
  __shared__ unsigned short Pb[64 * 72];

  const int qtA = blockIdx.x;           // 0..15
  const int qtB = 31 - qtA;             // 16..31
  const int qA0 = qtA * 64, qB0 = qtB * 64;
  const int qrowA = qA0 + w * 16 + lcol;
  const int qrowB = qB0 + w * 16 + lcol;
  const int prow  = w * 16 + lcol;

  // prefetch K/V tile 0 into registers
  uint4 kp0, kp1, vp0, vp1;
  {
    const unsigned short* gk = K + ((size_t)(bb * S_LEN + trow)) * DKV + hk * 64 + tq;
    kp0 = *(const uint4*)gk; kp1 = *(const uint4*)(gk + 8);
    const unsigned short* gv = Vt + ((size_t)(bb * DKV + hk * 64 + trow)) * S_LEN + tq;
    vp0 = *(const uint4*)gv; vp1 = *(const uint4*)(gv + 8);
  }

  { // stage both Q tiles (wave-private rows -> no barrier needed, just lgkm drain)
    const unsigned short* ga = Q + ((size_t)(bb * S_LEN + qA0 + trow)) * D_MODEL + hq * 64 + tq;
    *(uint4*)&Pa[trow * 72 + tq]     = *(const uint4*)ga;
    *(uint4*)&Pa[trow * 72 + tq + 8] = *(const uint4*)(ga + 8);
    const unsigned short* gb = Q + ((size_t)(bb * S_LEN + qB0 + trow)) * D_MODEL + hq * 64 + tq;
    *(uint4*)&Pb[trow * 72 + tq]     = *(const uint4*)gb;
    *(uint4*)&Pb[trow * 72 + tq + 8] = *(const uint4*)(gb + 8);
  }
  asm volatile("s_waitcnt lgkmcnt(0)" ::: "memory");

  short8 qfA[2], qfB[2];                // B-frags: n = q-row (w*16+lcol), k = d
#pragma unroll
  for (int ks = 0; ks < 2; ++ks) {
    qfA[ks] = *(const short8*)&Pa[prow * 72 + ks * 32 + lq * 8];
    qfB[ks] = *(const short8*)&Pb[prow * 72 + ks * 32 + lq * 8];
  }

  f32x4 OaccA[4] = {}, OaccB[4] = {};   // O^T: col = q-row, row = d = dt*16+lq*4+r
  float mA = -3e38f, lA = 0.f, mB = -3e38f, lB = 0.f;

  // online-softmax update for one tile's 16 scores (all belong to this lane's q-row)
  auto softmax_update = [&](f32x4 (&S)[4], float& m_i, float& l_i, f32x4 (&Oacc)[4],
                            unsigned short* P) {
    float mx = fmaxf(fmaxf(S[0][0], S[0][1]), fmaxf(S[0][2], S[0][3]));
#pragma unroll
    for (int nt = 1; nt < 4; ++nt)
      mx = fmaxf(mx, fmaxf(fmaxf(S[nt][0], S[nt][1]), fmaxf(S[nt][2], S[nt][3])));
    mx = fmaxf(mx, __shfl_xor(mx, 16));
    mx = fmaxf(mx, __shfl_xor(mx, 32));
    const float mnew  = fmaxf(m_i, mx);
    const float alpha = exp2f(m_i - mnew);
    float rs = 0.f;
#pragma unroll
    for (int nt = 0; nt < 4; ++nt)
#pragma unroll
      for (int r = 0; r < 4; ++r) {
        const float p = exp2f(S[nt][r] - mnew);
        S[nt][r] = p;
        rs += p;
      }
    rs += __shfl_xor(rs, 16);
    rs += __shfl_xor(rs, 32);
    m_i = mnew;
    l_i = l_i * alpha + rs;
#pragma unroll
    for (int dt = 0; dt < 4; ++dt) Oacc[dt] *= alpha;
    // P^T rows (wave-private), bf16 by truncation: 2 v_perm + 1 b64 store per nt
#pragma unroll
    for (int nt = 0; nt < 4; ++nt) {
      unsigned u2[2] = {packtrunc2(S[nt][0], S[nt][1]), packtrunc2(S[nt][2], S[nt][3])};
      *(uint2*)&P[prow * 72 + nt * 16 + lq * 4] = *(const uint2*)u2;
    }
  };

  for (int t = 0; t <= qtB; ++t) {
    __syncthreads();                    // all waves done reading Ks/Vts of iter t-1
    *(uint4*)&Ks[trow * 72 + tq]      = kp0;
    *(uint4*)&Ks[trow * 72 + tq + 8]  = kp1;
    *(uint4*)&Vts[trow * 72 + tq]     = vp0;
    *(uint4*)&Vts[trow * 72 + tq + 8] = vp1;
    if (t < qtB) {                      // prefetch next tile
      const int t1 = (t + 1) * 64;
      const unsigned short* gk = K + ((size_t)(bb * S_LEN + t1 + trow)) * DKV + hk * 64 + tq;
      kp0 = *(const uint4*)gk; kp1 = *(const uint4*)(gk + 8);
      const unsigned short* gv = Vt + ((size_t)(bb * DKV + hk * 64 + trow)) * S_LEN + t1 + tq;
      vp0 = *(const uint4*)gv; vp1 = *(const uint4*)(gv + 8);
    }
    __syncthreads();

    const bool actA = (t <= qtA);

    // ---- tile B scores: S^T = K @ Q^T ----
    f32x4 SB[4] = {};
#pragma unroll
    for (int ks = 0; ks < 2; ++ks)
#pragma unroll
      for (int nt = 0; nt < 4; ++nt) {
        const short8 kf = *(const short8*)&Ks[(nt * 16 + lcol) * 72 + ks * 32 + lq * 8];
        SB[nt] = __builtin_amdgcn_mfma_f32_16x16x32_bf16(kf, qfB[ks], SB[nt], 0, 0, 0);
      }
    if (t == qtB) {                     // diagonal tile for B
#pragma unroll
      for (int nt = 0; nt < 4; ++nt)
#pragma unroll
        for (int r = 0; r < 4; ++r) {
          const int key = t * 64 + nt * 16 + lq * 4 + r;
          if (key > qrowB) SB[nt][r] = -1e30f;
        }
    }
    softmax_update(SB, mB, lB, OaccB, Pb);

    // ---- tile A (active while t <= qtA) ----
    if (actA) {
      f32x4 SA[4] = {};
#pragma unroll
      for (int ks = 0; ks < 2; ++ks)
#pragma unroll
        for (int nt = 0; nt < 4; ++nt) {
          const short8 kf = *(const short8*)&Ks[(nt * 16 + lcol) * 72 + ks * 32 + lq * 8];
          SA[nt] = __builtin_amdgcn_mfma_f32_16x16x32_bf16(kf, qfA[ks], SA[nt], 0, 0, 0);
        }
      if (t == qtA) {                   // diagonal tile for A
#pragma unroll
        for (int nt = 0; nt < 4; ++nt)
#pragma unroll
          for (int r = 0; r < 4; ++r) {
            const int key = t * 64 + nt * 16 + lq * 4 + r;
            if (key > qrowA) SA[nt][r] = -1e30f;
          }
      }
      softmax_update(SA, mA, lA, OaccA, Pa);
    }
    asm volatile("s_waitcnt lgkmcnt(0)" ::: "memory");  // per-wave P write->read ordering

    // ---- O^T += V^T @ P^T ----
#pragma unroll
    for (int ks = 0; ks < 2; ++ks) {
      const short8 pfB = *(const short8*)&Pb[prow * 72 + ks * 32 + lq * 8];
#pragma unroll
      for (int dt = 0; dt < 4; ++dt) {
        const short8 vf = *(const short8*)&Vts[(dt * 16 + lcol) * 72 + ks * 32 + lq * 8];
        OaccB[dt] = __builtin_amdgcn_mfma_f32_16x16x32_bf16(vf, pfB, OaccB[dt], 0, 0, 0);
      }
    }
    if (actA) {
#pragma unroll
      for (int ks = 0; ks < 2; ++ks) {
        const short8 pfA = *(const short8*)&Pa[prow * 72 + ks * 32 + lq * 8];
#pragma unroll
        for (int dt = 0; dt < 4; ++dt) {
          const short8 vf = *(const short8*)&Vts[(dt * 16 + lcol) * 72 + ks * 32 + lq * 8];
          OaccA[dt] = __builtin_amdgcn_mfma_f32_16x16x32_bf16(vf, pfA, OaccA[dt], 0, 0, 0);
        }
      }
    }
  }

  // epilogue: lane owns q-rows qrowA/qrowB; d = dt*16 + lq*4 + r (contiguous -> b64 stores)
  const float invA = 1.0f / lA, invB = 1.0f / lB;
#pragma unroll
  for (int dt = 0; dt < 4; ++dt) {
    unsigned short ua[4] = {f2bf(OaccA[dt][0] * invA), f2bf(OaccA[dt][1] * invA),
                            f2bf(OaccA[dt][2] * invA), f2bf(OaccA[dt][3] * invA)};
    *(uint2*)&O[(size_t)(bb * S_LEN + qrowA) * D_MODEL + hq * 64 + dt * 16 + lq * 4] =
        *(const uint2*)ua;
    unsigned short ub[4] = {f2bf(OaccB[dt][0] * invB), f2bf(OaccB[dt][1] * invB),
                            f2bf(OaccB[dt][2] * invB), f2bf(OaccB[dt][3] * invB)};
    *(uint2*)&O[(size_t)(bb * S_LEN + qrowB) * D_MODEL + hq * 64 + dt * 16 + lq * 4] =
        *(const uint2*)ub;
  }
}

extern "C" void kernel_launch(void* const* d_in, const int* in_sizes, int n_in,
                              void* d_out, int out_size, void* d_ws, size_t ws_size,
                              hipStream_t stream) {
  const float* x  = (const float*)d_in[0];   // fp32 inputs per the reference dtypes
  const float* Wq = (const float*)d_in[1];
  const float* Wk = (const float*)d_in[2];
  const float* Wv = (const float*)d_in[3];
  const float* Wo = (const float*)d_in[4];
  float* out = (float*)d_out;                // fp32 output per the reference

  // Workspace (bf16 elements), total ~70 MiB:
  unsigned short* Qb  = (unsigned short*)d_ws;                 // 4096 x 2048
  unsigned short* Kb  = Qb  + (size_t)4096 * 2048;             // 4096 x 512
  unsigned short* Vtg = Kb  + (size_t)4096 * 512;              // 1024 x 2048 (V pre-transposed)
  unsigned short* Ab  = Vtg + (size_t)1024 * 2048;             // 4096 x 2048
  unsigned short* xb  = Ab  + (size_t)4096 * 2048;             // 4096 x 2048
  unsigned short* Wqb = xb  + (size_t)4096 * 2048;             // 2048 x 2048
  unsigned short* Wkb = Wqb + (size_t)2048 * 2048;             // 512 x 2048
  unsigned short* Wvb = Wkb + (size_t)512 * 2048;              // 512 x 2048
  unsigned short* Wob = Wvb + (size_t)512 * 2048;              // 2048 x 2048

  cvt_all_kernel<<<9216, 256, 0, stream>>>(x, Wq, Wk, Wv, Wo, xb, Wqb, Wkb, Wvb, Wob);

  qkv_gemm_kernel<<<dim3(24, 32), 256, 0, stream>>>(xb, Wqb, Wkb, Wvb, Qb, Kb, Vtg);
  rope_both_kernel<<<20480, 256, 0, stream>>>(Qb, Kb);
  attn_kernel<<<dim3(16, 32, 2), 256, 0, stream>>>(Qb, Kb, Vtg, Ab);
  oproj_gemm_kernel<<<dim3(16, 32), 256, 0, stream>>>(Ab, Wob, out);
}